// Round 20
// baseline (194.227 us; speedup 1.0000x reference)
//
#include <hip/hip_runtime.h>
#include <hip/hip_bf16.h>
#include <hip/hip_fp16.h>

typedef __attribute__((ext_vector_type(8))) short short8;
typedef __attribute__((ext_vector_type(4))) short s16x4;
typedef __attribute__((ext_vector_type(4))) float f32x4;

#define BN 4
#define PN 1024
#define NN 16
#define C1N 64
#define C2N 64
#define KN 13
#define AN 12
#define KDIM 9984   // C1N*KN*AN, kk = k*768 + c*12 + a  (k=12 slice at 9216+)
#define NDIM 768    // C2N*AN
#define MDIM 4096   // BN*PN
#define NSPLIT 4    // 39 steps of BK=64 each (156 total)
#define BK 64
#define BM 128      // GEMM block tile M
#define BNT 192     // GEMM block tile N (4 waves x 48)
#define NSTEPS 39

__device__ inline unsigned short f2bf(float x){
    unsigned int u = __float_as_uint(x);
    unsigned int r = (u + 0x7fffu + ((u >> 16) & 1u)) >> 16;
    return (unsigned short)r;
}
__device__ inline f32x4 bf4_to_f(s16x4 h){
    f32x4 r;
    r[0] = __uint_as_float(((unsigned)(unsigned short)h[0]) << 16);
    r[1] = __uint_as_float(((unsigned)(unsigned short)h[1]) << 16);
    r[2] = __uint_as_float(((unsigned)(unsigned short)h[2]) << 16);
    r[3] = __uint_as_float(((unsigned)(unsigned short)h[3]) << 16);
    return r;
}

// async global->LDS, 16B per lane. LDS dest = wave-uniform base + lane*16.
__device__ __forceinline__ void gload16(const unsigned short* g, unsigned short* l){
    __builtin_amdgcn_global_load_lds(
        (const __attribute__((address_space(1))) unsigned int*)(unsigned long long)(uintptr_t)g,
        (__attribute__((address_space(3))) unsigned int*)(unsigned int)(uintptr_t)l,
        16, 0, 0);
}

// ================= Kernel 1: fused prep (interw | beff-LDS | tr) — R15-proven =================
__global__ __launch_bounds__(256) void k_prep(const int* __restrict__ nbr,
                                              const float* __restrict__ vert,
                                              const float* __restrict__ vs,
                                              const float* __restrict__ W,
                                              const int* __restrict__ idx_map,
                                              const int* __restrict__ tiv,
                                              const int* __restrict__ tir,
                                              const float* __restrict__ fm,
                                              float* __restrict__ iw,
                                              unsigned short* __restrict__ Bm,
                                              unsigned short* __restrict__ Am)
{
    __shared__ float Wl[64][37];     // +1 pad: bank (37c+s)%32 cycles all banks
    __shared__ int   s36s[KN][AN];
    int bid = blockIdx.x;
    int t = threadIdx.x;
    if (bid < 192){
        int tt = bid * 256 + t;               // < 49152
        int pt = tt / AN, a = tt - pt * AN;
        int b = pt >> 10;
        float sx = vs[a*3+0], sy = vs[a*3+1], sz = vs[a*3+2];
        float sn = sqrtf(sx*sx + sy*sy + sz*sz);
        float si = 1.0f / fmaxf(sn, 1e-12f);
        sx *= si; sy *= si; sz *= si;
        float vx = vert[pt*3+0], vy = vert[pt*3+1], vz = vert[pt*3+2];
        float tv[NN];
        float mx = -1e30f;
        #pragma unroll
        for (int n = 0; n < NN; n++){
            int g = (b << 10) + nbr[pt*NN + n];
            float dx = vert[g*3+0] - vx;
            float dy = vert[g*3+1] - vy;
            float dz = vert[g*3+2] - vz;
            float nr = sqrtf(dx*dx + dy*dy + dz*dz);
            float inv = 1.0f / fmaxf(nr, 1e-12f);
            tv[n] = (dx*sx + dy*sy + dz*sz) * inv;
            mx = fmaxf(mx, tv[n]);
        }
        float s = 0.0f;
        #pragma unroll
        for (int n = 0; n < NN; n++){ tv[n] = expf(tv[n] - mx); s += tv[n]; }
        float inv = 1.0f / s;
        float* dst = iw + (size_t)tt * NN;
        #pragma unroll
        for (int q = 0; q < 4; q++){
            float4 v = make_float4(tv[q*4]*inv, tv[q*4+1]*inv, tv[q*4+2]*inv, tv[q*4+3]*inv);
            *(float4*)(dst + q*4) = v;
        }
    } else if (bid < 960){
        // ---- beff: one block per (d,r) = bid-192 ----
        int dr = bid - 192;
        int d = dr / AN, r = dr - d*AN;
        for (int i = t; i < C1N*36; i += 256){
            int c = i / 36, s = i - c*36;
            Wl[c][s] = W[(size_t)d * (C1N*36) + i];
        }
        if (t < KN*AN){
            int k = t / AN, a = t - (t/AN)*AN;
            s36s[k][a] = idx_map[ tiv[r*KN + k]*AN + tir[r*AN + a] ];
        }
        __syncthreads();
        int c = t & 63, kq = t >> 6;          // 4 k-groups per block
        unsigned short* brow = Bm + (size_t)dr * KDIM + c*AN;
        for (int k = kq; k < KN; k += 4){
            s16x4 v0, v1, v2;
            #pragma unroll
            for (int a = 0; a < AN; a++){
                unsigned short h = f2bf(Wl[c][s36s[k][a]]);
                if (a < 4) v0[a] = (short)h;
                else if (a < 8) v1[a-4] = (short)h;
                else v2[a-8] = (short)h;
            }
            s16x4* o = (s16x4*)(brow + k*768);
            o[0] = v0; o[1] = v1; o[2] = v2;
        }
    } else {
        // ---- tr: thread per (b,c,p): fm row -> Am[m][9216 + c*12 .. +12] ----
        int t2 = (bid - 960) * 256 + t;       // < 262144
        int p = t2 & 1023;
        int bc = t2 >> 10;
        int c = bc & 63, b = bc >> 6;
        const float* src = fm + (size_t)t2 * 12;
        float4 v0 = *(const float4*)(src);
        float4 v1 = *(const float4*)(src + 4);
        float4 v2 = *(const float4*)(src + 8);
        s16x4 h0, h1, h2;
        h0[0]=(short)f2bf(v0.x); h0[1]=(short)f2bf(v0.y); h0[2]=(short)f2bf(v0.z); h0[3]=(short)f2bf(v0.w);
        h1[0]=(short)f2bf(v1.x); h1[1]=(short)f2bf(v1.y); h1[2]=(short)f2bf(v1.z); h1[3]=(short)f2bf(v1.w);
        h2[0]=(short)f2bf(v2.x); h2[1]=(short)f2bf(v2.y); h2[2]=(short)f2bf(v2.z); h2[3]=(short)f2bf(v2.w);
        int m = (b << 10) + p;
        s16x4* o = (s16x4*)(Am + (size_t)m * KDIM + 9216 + c*12);
        o[0] = h0; o[1] = h1; o[2] = h2;
    }
}

// ---------------- Kernel 3: new_feat k=0..11 -> Am[m][k*768+c*12+a] — R10-proven ----------------
__global__ __launch_bounds__(256) void k_newfeat(const int* __restrict__ nbr,
                                                 const float* __restrict__ iw,
                                                 unsigned short* Am)
{
    __shared__ int   nbs_s[2][NN];
    __shared__ float iwT_s[2][NN][AN];
    int t = threadIdx.x;
    int w = t >> 6, lane = t & 63;
    int pw = w >> 1, khalf = w & 1;
    int m = blockIdx.x * 2 + pw;
    int b = m >> 10;

    if (khalf == 0){
        if (lane < NN) nbs_s[pw][lane] = nbr[m*NN + lane];
        #pragma unroll
        for (int i = 0; i < 3; i++){
            int idx = lane + i*64;
            int a = idx >> 4, n = idx & 15;
            iwT_s[pw][n][a] = iw[(size_t)m * (AN*NN) + idx];
        }
    }
    __syncthreads();

    f32x4 acc[6][3];
    #pragma unroll
    for (int k = 0; k < 6; k++)
        #pragma unroll
        for (int q = 0; q < 3; q++) acc[k][q] = (f32x4){0.f,0.f,0.f,0.f};

    int kb = khalf * 6;
    const unsigned short* slice = Am + 9216 + (size_t)lane * AN;

    #pragma unroll 2
    for (int n = 0; n < NN; n++){
        int mn = (b << 10) + nbs_s[pw][n];
        const unsigned short* src = slice + (size_t)mn * KDIM;
        s16x4 u0 = *(const s16x4*)(src);
        s16x4 u1 = *(const s16x4*)(src + 4);
        s16x4 u2 = *(const s16x4*)(src + 8);
        f32x4 v0 = bf4_to_f(u0), v1 = bf4_to_f(u1), v2 = bf4_to_f(u2);
        #pragma unroll
        for (int k = 0; k < 6; k++){
            float wv = iwT_s[pw][n][kb + k];
            acc[k][0] += v0 * wv;
            acc[k][1] += v1 * wv;
            acc[k][2] += v2 * wv;
        }
    }

    unsigned short* dst = Am + (size_t)m * KDIM + lane * AN;
    #pragma unroll
    for (int k = 0; k < 6; k++){
        s16x4 h0, h1, h2;
        #pragma unroll
        for (int j = 0; j < 4; j++){
            h0[j] = (short)f2bf(acc[k][0][j]);
            h1[j] = (short)f2bf(acc[k][1][j]);
            h2[j] = (short)f2bf(acc[k][2][j]);
        }
        s16x4* o = (s16x4*)(dst + (kb + k)*768);
        o[0] = h0; o[1] = h1; o[2] = h2;
    }
}

// ---------------- Kernel 4: GEMM 128x192 (R19-exact loop) + atomic fp32 epilogue ----------------
// Per-wave 64x48 (2M x 4N waves, acc 4x3). LDS 80 KB -> 2 blocks/CU (proven 60.4 us loop).
// Sync skeleton (R10-proven): barrier -> ISSUE(s+1) -> vmcnt(5) -> barrier -> BODY(s).
// T2 swizzle: source chunk ch^(row&7), same XOR on read (involution; measured 0 conflicts).
// R20 change: split-K partials eliminated — out is zeroed (hipMemsetAsync) and each z-block
// atomicAdds its fp32 contribution directly into the bdpr layout. Removes k_reduce (+ its
// launch gap) and the 50 MB part round-trip; ~200 MB of L2-side atomic RMW absorbs it.
__global__ __launch_bounds__(512, 4) void k_gemm(const unsigned short* __restrict__ Am,
                                                 const unsigned short* __restrict__ Bm,
                                                 float* __restrict__ out)
{
    __shared__ unsigned short Al[2][BM*BK];    // 2 x 16 KB
    __shared__ unsigned short Bl[2][BNT*BK];   // 2 x 24 KB
    int t = threadIdx.x;
    int lane = t & 63, w = t >> 6;
    int wr = w >> 2, wc = w & 3;               // 2M x 4N
    int l15 = lane & 15;
    int lq  = lane >> 4;                       // k-chunk slot 0..3
    int m0 = blockIdx.x * BM, n0 = blockIdx.y * BNT;
    int z = blockIdx.z;
    int kbase = z * NSTEPS * BK;               // z*2496

    // A staging: 1024 chunks / 512 threads = 2 each; B: 1536 chunks / 512 = 3 each.
    const unsigned short* gA[2];
    const unsigned short* gB[3];
    int lofsA[2], lofsB[3];
    #pragma unroll
    for (int i = 0; i < 2; i++){
        int g = i*512 + t;
        int row = g >> 3, ch = g & 7;
        int sch = ch ^ (row & 7);
        gA[i] = Am + (size_t)(m0 + row) * KDIM + kbase + sch*8;
        lofsA[i] = g * 8;
    }
    #pragma unroll
    for (int i = 0; i < 3; i++){
        int g = i*512 + t;
        int row = g >> 3, ch = g & 7;
        int sch = ch ^ (row & 7);
        gB[i] = Bm + (size_t)(n0 + row) * KDIM + kbase + sch*8;
        lofsB[i] = g * 8;
    }

    f32x4 acc[4][3] = {};

#define ISSUE(S,KK) {                                                    \
        _Pragma("unroll")                                                \
        for (int i = 0; i < 2; i++) gload16(gA[i] + (KK), &Al[(S)&1][lofsA[i]]); \
        _Pragma("unroll")                                                \
        for (int i = 0; i < 3; i++) gload16(gB[i] + (KK), &Bl[(S)&1][lofsB[i]]); }

#define BODY(S) { const int cur_ = (S) & 1;                              \
        _Pragma("unroll")                                                \
        for (int kh = 0; kh < 2; kh++){                                  \
            int cc = kh*4 + lq;                                          \
            short8 af[4], bf[3];                                         \
            _Pragma("unroll")                                            \
            for (int i = 0; i < 4; i++){                                 \
                int ra = wr*64 + i*16 + l15;                             \
                af[i] = *(const short8*)&Al[cur_][ra*BK + ((cc ^ (ra & 7)) * 8)]; \
            }                                                            \
            _Pragma("unroll")                                            \
            for (int j = 0; j < 3; j++){                                 \
                int rb = wc*48 + j*16 + l15;                             \
                bf[j] = *(const short8*)&Bl[cur_][rb*BK + ((cc ^ (rb & 7)) * 8)]; \
            }                                                            \
            _Pragma("unroll")                                            \
            for (int i = 0; i < 4; i++){                                 \
                _Pragma("unroll")                                        \
                for (int j = 0; j < 3; j++)                              \
                    acc[i][j] = __builtin_amdgcn_mfma_f32_16x16x32_bf16(af[i], bf[j], acc[i][j], 0, 0, 0); \
            }                                                            \
        } }

    // prologue: stage tile 0 into buffer 0
    ISSUE(0, 0);

    for (int s = 0; s < NSTEPS; ++s){
        __builtin_amdgcn_s_barrier();            // WAR: all waves done reading buf[(s+1)&1]
        if (s + 1 < NSTEPS){
            ISSUE(s + 1, (s + 1) * BK);
            asm volatile("s_waitcnt vmcnt(5)" ::: "memory");
        } else {
            asm volatile("s_waitcnt vmcnt(0)" ::: "memory");
        }
        __builtin_amdgcn_s_barrier();            // RAW: every wave's batch-s loads landed
        BODY(s);
    }
#undef ISSUE
#undef BODY

    // epilogue: atomic fp32 accumulate into bdpr. C/D layout col=lane&15, row=(lane>>4)*4+q.
    #pragma unroll
    for (int i = 0; i < 4; i++){
        #pragma unroll
        for (int j = 0; j < 3; j++){
            int col = n0 + wc*48 + j*16 + l15;
            int d = col / AN, r = col - d*AN;
            #pragma unroll
            for (int q = 0; q < 4; q++){
                int row = m0 + wr*64 + i*16 + (lane >> 4)*4 + q;
                int b = row >> 10, p = row & 1023;
                atomicAdd(out + ((size_t)((b << 6) + d) * PN + p) * AN + r, acc[i][j][q]);
            }
        }
    }
}

extern "C" void kernel_launch(void* const* d_in, const int* in_sizes, int n_in,
                              void* d_out, int out_size, void* d_ws, size_t ws_size,
                              hipStream_t stream)
{
    const int*   nbr     = (const int*)  d_in[0];
    const float* vert    = (const float*)d_in[1];
    const float* fm      = (const float*)d_in[2];
    const float* W       = (const float*)d_in[3];
    const float* vs      = (const float*)d_in[4];
    const int*   idx_map = (const int*)  d_in[5];
    const int*   tiv     = (const int*)  d_in[6];
    const int*   tir     = (const int*)  d_in[7];
    float* out = (float*)d_out;

    char* ws = (char*)d_ws;
    float*          iw   = (float*)ws;                                  // 3,145,728 B
    unsigned short* Bm   = (unsigned short*)(ws + 3145728);             // 15,335,424 B
    unsigned short* Am   = (unsigned short*)(ws + 18481152);            // 81,788,928 B

    // zero the output (accumulated atomically by k_gemm); stream memset is graph-capturable
    hipMemsetAsync(out, 0, (size_t)MDIM * NDIM * sizeof(float), stream);

    k_prep   <<<1984, 256, 0, stream>>>(nbr, vert, vs, W, idx_map, tiv, tir, fm, iw, Bm, Am);
    k_newfeat<<<MDIM/2, 256, 0, stream>>>(nbr, iw, Am);
    dim3 g(MDIM/BM, NDIM/BNT, NSPLIT);
    k_gemm   <<<g, 512, 0, stream>>>(Am, Bm, out);
}

// Round 21
// 115.301 us; speedup vs baseline: 1.6845x; 1.6845x over previous
//
#include <hip/hip_runtime.h>
#include <hip/hip_bf16.h>
#include <hip/hip_fp16.h>

typedef __attribute__((ext_vector_type(8))) short short8;
typedef __attribute__((ext_vector_type(4))) short s16x4;
typedef __attribute__((ext_vector_type(4))) float f32x4;

#define BN 4
#define PN 1024
#define NN 16
#define C1N 64
#define C2N 64
#define KN 13
#define AN 12
#define KDIM 9984   // C1N*KN*AN, kk = k*768 + c*12 + a  (k=12 slice at 9216+)
#define NDIM 768    // C2N*AN
#define MDIM 4096   // BN*PN
#define NSPLIT 4    // 39 steps of BK=64 each (156 total)
#define BK 64
#define BM 128      // GEMM block tile M
#define BNT 192     // GEMM block tile N (4 waves x 48)
#define NSTEPS 39

__device__ inline unsigned short f2bf(float x){
    unsigned int u = __float_as_uint(x);
    unsigned int r = (u + 0x7fffu + ((u >> 16) & 1u)) >> 16;
    return (unsigned short)r;
}
__device__ inline f32x4 bf4_to_f(s16x4 h){
    f32x4 r;
    r[0] = __uint_as_float(((unsigned)(unsigned short)h[0]) << 16);
    r[1] = __uint_as_float(((unsigned)(unsigned short)h[1]) << 16);
    r[2] = __uint_as_float(((unsigned)(unsigned short)h[2]) << 16);
    r[3] = __uint_as_float(((unsigned)(unsigned short)h[3]) << 16);
    return r;
}

// async global->LDS, 16B per lane. LDS dest = wave-uniform base + lane*16.
__device__ __forceinline__ void gload16(const unsigned short* g, unsigned short* l){
    __builtin_amdgcn_global_load_lds(
        (const __attribute__((address_space(1))) unsigned int*)(unsigned long long)(uintptr_t)g,
        (__attribute__((address_space(3))) unsigned int*)(unsigned int)(uintptr_t)l,
        16, 0, 0);
}

// ================= Kernel 1: fused prep (interw | beff-LDS | tr) — R15-proven =================
__global__ __launch_bounds__(256) void k_prep(const int* __restrict__ nbr,
                                              const float* __restrict__ vert,
                                              const float* __restrict__ vs,
                                              const float* __restrict__ W,
                                              const int* __restrict__ idx_map,
                                              const int* __restrict__ tiv,
                                              const int* __restrict__ tir,
                                              const float* __restrict__ fm,
                                              float* __restrict__ iw,
                                              unsigned short* __restrict__ Bm,
                                              unsigned short* __restrict__ Am)
{
    __shared__ float Wl[64][37];     // +1 pad: bank (37c+s)%32 cycles all banks
    __shared__ int   s36s[KN][AN];
    int bid = blockIdx.x;
    int t = threadIdx.x;
    if (bid < 192){
        int tt = bid * 256 + t;               // < 49152
        int pt = tt / AN, a = tt - pt * AN;
        int b = pt >> 10;
        float sx = vs[a*3+0], sy = vs[a*3+1], sz = vs[a*3+2];
        float sn = sqrtf(sx*sx + sy*sy + sz*sz);
        float si = 1.0f / fmaxf(sn, 1e-12f);
        sx *= si; sy *= si; sz *= si;
        float vx = vert[pt*3+0], vy = vert[pt*3+1], vz = vert[pt*3+2];
        float tv[NN];
        float mx = -1e30f;
        #pragma unroll
        for (int n = 0; n < NN; n++){
            int g = (b << 10) + nbr[pt*NN + n];
            float dx = vert[g*3+0] - vx;
            float dy = vert[g*3+1] - vy;
            float dz = vert[g*3+2] - vz;
            float nr = sqrtf(dx*dx + dy*dy + dz*dz);
            float inv = 1.0f / fmaxf(nr, 1e-12f);
            tv[n] = (dx*sx + dy*sy + dz*sz) * inv;
            mx = fmaxf(mx, tv[n]);
        }
        float s = 0.0f;
        #pragma unroll
        for (int n = 0; n < NN; n++){ tv[n] = expf(tv[n] - mx); s += tv[n]; }
        float inv = 1.0f / s;
        float* dst = iw + (size_t)tt * NN;
        #pragma unroll
        for (int q = 0; q < 4; q++){
            float4 v = make_float4(tv[q*4]*inv, tv[q*4+1]*inv, tv[q*4+2]*inv, tv[q*4+3]*inv);
            *(float4*)(dst + q*4) = v;
        }
    } else if (bid < 960){
        // ---- beff: one block per (d,r) = bid-192 ----
        int dr = bid - 192;
        int d = dr / AN, r = dr - d*AN;
        for (int i = t; i < C1N*36; i += 256){
            int c = i / 36, s = i - c*36;
            Wl[c][s] = W[(size_t)d * (C1N*36) + i];
        }
        if (t < KN*AN){
            int k = t / AN, a = t - (t/AN)*AN;
            s36s[k][a] = idx_map[ tiv[r*KN + k]*AN + tir[r*AN + a] ];
        }
        __syncthreads();
        int c = t & 63, kq = t >> 6;          // 4 k-groups per block
        unsigned short* brow = Bm + (size_t)dr * KDIM + c*AN;
        for (int k = kq; k < KN; k += 4){
            s16x4 v0, v1, v2;
            #pragma unroll
            for (int a = 0; a < AN; a++){
                unsigned short h = f2bf(Wl[c][s36s[k][a]]);
                if (a < 4) v0[a] = (short)h;
                else if (a < 8) v1[a-4] = (short)h;
                else v2[a-8] = (short)h;
            }
            s16x4* o = (s16x4*)(brow + k*768);
            o[0] = v0; o[1] = v1; o[2] = v2;
        }
    } else {
        // ---- tr: thread per (b,c,p): fm row -> Am[m][9216 + c*12 .. +12] ----
        int t2 = (bid - 960) * 256 + t;       // < 262144
        int p = t2 & 1023;
        int bc = t2 >> 10;
        int c = bc & 63, b = bc >> 6;
        const float* src = fm + (size_t)t2 * 12;
        float4 v0 = *(const float4*)(src);
        float4 v1 = *(const float4*)(src + 4);
        float4 v2 = *(const float4*)(src + 8);
        s16x4 h0, h1, h2;
        h0[0]=(short)f2bf(v0.x); h0[1]=(short)f2bf(v0.y); h0[2]=(short)f2bf(v0.z); h0[3]=(short)f2bf(v0.w);
        h1[0]=(short)f2bf(v1.x); h1[1]=(short)f2bf(v1.y); h1[2]=(short)f2bf(v1.z); h1[3]=(short)f2bf(v1.w);
        h2[0]=(short)f2bf(v2.x); h2[1]=(short)f2bf(v2.y); h2[2]=(short)f2bf(v2.z); h2[3]=(short)f2bf(v2.w);
        int m = (b << 10) + p;
        s16x4* o = (s16x4*)(Am + (size_t)m * KDIM + 9216 + c*12);
        o[0] = h0; o[1] = h1; o[2] = h2;
    }
}

// ---------------- Kernel 3: new_feat k=0..11 -> Am[m][k*768+c*12+a] — R10-proven ----------------
__global__ __launch_bounds__(256) void k_newfeat(const int* __restrict__ nbr,
                                                 const float* __restrict__ iw,
                                                 unsigned short* Am)
{
    __shared__ int   nbs_s[2][NN];
    __shared__ float iwT_s[2][NN][AN];
    int t = threadIdx.x;
    int w = t >> 6, lane = t & 63;
    int pw = w >> 1, khalf = w & 1;
    int m = blockIdx.x * 2 + pw;
    int b = m >> 10;

    if (khalf == 0){
        if (lane < NN) nbs_s[pw][lane] = nbr[m*NN + lane];
        #pragma unroll
        for (int i = 0; i < 3; i++){
            int idx = lane + i*64;
            int a = idx >> 4, n = idx & 15;
            iwT_s[pw][n][a] = iw[(size_t)m * (AN*NN) + idx];
        }
    }
    __syncthreads();

    f32x4 acc[6][3];
    #pragma unroll
    for (int k = 0; k < 6; k++)
        #pragma unroll
        for (int q = 0; q < 3; q++) acc[k][q] = (f32x4){0.f,0.f,0.f,0.f};

    int kb = khalf * 6;
    const unsigned short* slice = Am + 9216 + (size_t)lane * AN;

    #pragma unroll 2
    for (int n = 0; n < NN; n++){
        int mn = (b << 10) + nbs_s[pw][n];
        const unsigned short* src = slice + (size_t)mn * KDIM;
        s16x4 u0 = *(const s16x4*)(src);
        s16x4 u1 = *(const s16x4*)(src + 4);
        s16x4 u2 = *(const s16x4*)(src + 8);
        f32x4 v0 = bf4_to_f(u0), v1 = bf4_to_f(u1), v2 = bf4_to_f(u2);
        #pragma unroll
        for (int k = 0; k < 6; k++){
            float wv = iwT_s[pw][n][kb + k];
            acc[k][0] += v0 * wv;
            acc[k][1] += v1 * wv;
            acc[k][2] += v2 * wv;
        }
    }

    unsigned short* dst = Am + (size_t)m * KDIM + lane * AN;
    #pragma unroll
    for (int k = 0; k < 6; k++){
        s16x4 h0, h1, h2;
        #pragma unroll
        for (int j = 0; j < 4; j++){
            h0[j] = (short)f2bf(acc[k][0][j]);
            h1[j] = (short)f2bf(acc[k][1][j]);
            h2[j] = (short)f2bf(acc[k][2][j]);
        }
        s16x4* o = (s16x4*)(dst + (kb + k)*768);
        o[0] = h0; o[1] = h1; o[2] = h2;
    }
}

// ---------------- Kernel 4: GEMM 128x192, 8 waves, dbuf BK=64, counted vmcnt (R19-exact) ----------------
// Per-wave 64x48 (2M x 4N waves, acc 4x3). Per kh-phase: 7 ds_read_b128 per 12 MFMA.
// LDS = 2x16(A) + 2x24(B) = 80 KB -> 2 blocks/CU (160 KiB exact). Measured 60.4 us (1040 TF).
// Sync skeleton (R10-proven): barrier -> ISSUE(s+1) -> vmcnt(5) -> barrier -> BODY(s).
// T2 swizzle: source chunk ch^(row&7), same XOR on read (involution; measured 0 conflicts).
// Grid 32x4x4 = 512 blocks = exact 2-per-CU residency footprint.
__global__ __launch_bounds__(512, 4) void k_gemm(const unsigned short* __restrict__ Am,
                                                 const unsigned short* __restrict__ Bm,
                                                 __half* __restrict__ part)
{
    __shared__ unsigned short Al[2][BM*BK];    // 2 x 16 KB
    __shared__ unsigned short Bl[2][BNT*BK];   // 2 x 24 KB
    int t = threadIdx.x;
    int lane = t & 63, w = t >> 6;
    int wr = w >> 2, wc = w & 3;               // 2M x 4N
    int l15 = lane & 15;
    int lq  = lane >> 4;                       // k-chunk slot 0..3
    int m0 = blockIdx.x * BM, n0 = blockIdx.y * BNT;
    int z = blockIdx.z;
    int kbase = z * NSTEPS * BK;               // z*2496

    // A staging: 1024 chunks / 512 threads = 2 each; B: 1536 chunks / 512 = 3 each.
    // g -> row = g>>3, ch = g&7; source chunk = ch^(row&7) (involution).
    const unsigned short* gA[2];
    const unsigned short* gB[3];
    int lofsA[2], lofsB[3];
    #pragma unroll
    for (int i = 0; i < 2; i++){
        int g = i*512 + t;
        int row = g >> 3, ch = g & 7;
        int sch = ch ^ (row & 7);
        gA[i] = Am + (size_t)(m0 + row) * KDIM + kbase + sch*8;
        lofsA[i] = g * 8;
    }
    #pragma unroll
    for (int i = 0; i < 3; i++){
        int g = i*512 + t;
        int row = g >> 3, ch = g & 7;
        int sch = ch ^ (row & 7);
        gB[i] = Bm + (size_t)(n0 + row) * KDIM + kbase + sch*8;
        lofsB[i] = g * 8;
    }

    f32x4 acc[4][3] = {};

#define ISSUE(S,KK) {                                                    \
        _Pragma("unroll")                                                \
        for (int i = 0; i < 2; i++) gload16(gA[i] + (KK), &Al[(S)&1][lofsA[i]]); \
        _Pragma("unroll")                                                \
        for (int i = 0; i < 3; i++) gload16(gB[i] + (KK), &Bl[(S)&1][lofsB[i]]); }

#define BODY(S) { const int cur_ = (S) & 1;                              \
        _Pragma("unroll")                                                \
        for (int kh = 0; kh < 2; kh++){                                  \
            int cc = kh*4 + lq;                                          \
            short8 af[4], bf[3];                                         \
            _Pragma("unroll")                                            \
            for (int i = 0; i < 4; i++){                                 \
                int ra = wr*64 + i*16 + l15;                             \
                af[i] = *(const short8*)&Al[cur_][ra*BK + ((cc ^ (ra & 7)) * 8)]; \
            }                                                            \
            _Pragma("unroll")                                            \
            for (int j = 0; j < 3; j++){                                 \
                int rb = wc*48 + j*16 + l15;                             \
                bf[j] = *(const short8*)&Bl[cur_][rb*BK + ((cc ^ (rb & 7)) * 8)]; \
            }                                                            \
            _Pragma("unroll")                                            \
            for (int i = 0; i < 4; i++){                                 \
                _Pragma("unroll")                                        \
                for (int j = 0; j < 3; j++)                              \
                    acc[i][j] = __builtin_amdgcn_mfma_f32_16x16x32_bf16(af[i], bf[j], acc[i][j], 0, 0, 0); \
            }                                                            \
        } }

    // prologue: stage tile 0 into buffer 0
    ISSUE(0, 0);

    for (int s = 0; s < NSTEPS; ++s){
        __builtin_amdgcn_s_barrier();            // WAR: all waves done reading buf[(s+1)&1]
        if (s + 1 < NSTEPS){
            ISSUE(s + 1, (s + 1) * BK);
            asm volatile("s_waitcnt vmcnt(5)" ::: "memory");
        } else {
            asm volatile("s_waitcnt vmcnt(0)" ::: "memory");
        }
        __builtin_amdgcn_s_barrier();            // RAW: every wave's batch-s loads landed
        BODY(s);
    }
#undef ISSUE
#undef BODY

    // epilogue: fp16 partials. C/D layout col=lane&15, row=(lane>>4)*4+q [m89-verified]
    __half* pp = part + (size_t)z * ((size_t)MDIM * NDIM);
    #pragma unroll
    for (int i = 0; i < 4; i++){
        #pragma unroll
        for (int j = 0; j < 3; j++){
            int col = n0 + wc*48 + j*16 + l15;
            #pragma unroll
            for (int q = 0; q < 4; q++){
                int row = m0 + wr*64 + i*16 + (lane >> 4)*4 + q;
                pp[(size_t)row * NDIM + col] = __float2half(acc[i][j][q]);
            }
        }
    }
}

// ---------------- Kernel 5: split-K reduce (fp16 partials) + scatter to bdpr ----------------
__global__ __launch_bounds__(256) void k_reduce(const __half* __restrict__ part,
                                                float* __restrict__ out)
{
    int t = blockIdx.x * 256 + threadIdx.x;
    if (t >= MDIM * (NDIM/4)) return;
    int m = t / (NDIM/4);
    int n4 = (t - m * (NDIM/4)) * 4;
    f32x4 s = {};
    #pragma unroll
    for (int z = 0; z < NSPLIT; z++){
        const __half2* pz = (const __half2*)(part + (size_t)z * ((size_t)MDIM * NDIM) + (size_t)m * NDIM + n4);
        float2 a = __half22float2(pz[0]);
        float2 b = __half22float2(pz[1]);
        s[0] += a.x; s[1] += a.y; s[2] += b.x; s[3] += b.y;
    }
    int b = m >> 10, p = m & 1023;
    int d = n4 / AN, r = n4 - d*AN;
    *(f32x4*)(out + ((size_t)((b << 6) + d) * PN + p) * AN + r) = s;
}

extern "C" void kernel_launch(void* const* d_in, const int* in_sizes, int n_in,
                              void* d_out, int out_size, void* d_ws, size_t ws_size,
                              hipStream_t stream)
{
    const int*   nbr     = (const int*)  d_in[0];
    const float* vert    = (const float*)d_in[1];
    const float* fm      = (const float*)d_in[2];
    const float* W       = (const float*)d_in[3];
    const float* vs      = (const float*)d_in[4];
    const int*   idx_map = (const int*)  d_in[5];
    const int*   tiv     = (const int*)  d_in[6];
    const int*   tir     = (const int*)  d_in[7];
    float* out = (float*)d_out;

    char* ws = (char*)d_ws;
    float*          iw   = (float*)ws;                                  // 3,145,728 B
    unsigned short* Bm   = (unsigned short*)(ws + 3145728);             // 15,335,424 B
    unsigned short* Am   = (unsigned short*)(ws + 18481152);            // 81,788,928 B
    __half*         part = (__half*)(ws + 100270080);                   // 25,165,824 B (4 x fp16)

    k_prep   <<<1984, 256, 0, stream>>>(nbr, vert, vs, W, idx_map, tiv, tir, fm, iw, Bm, Am);
    k_newfeat<<<MDIM/2, 256, 0, stream>>>(nbr, iw, Am);
    dim3 g(MDIM/BM, NDIM/BNT, NSPLIT);
    k_gemm   <<<g, 512, 0, stream>>>(Am, Bm, part);
    k_reduce <<<(MDIM*(NDIM/4))/256, 256, 0, stream>>>(part, out);
}